// Round 2
// baseline (129.251 us; speedup 1.0000x reference)
//
#include <hip/hip_runtime.h>
#include <hip/hip_bf16.h>
#include <math.h>

#define N_NODES 8192
#define F_IN    512
#define C_OUT   128
#define EDGE_CAP 512
#define NEG_SLOPE 0.2f

typedef float f4v __attribute__((ext_vector_type(4)));

// ---------------------------------------------------------------------------
// Kernel 1: ft = X @ W  (8192x512 @ 512x128), fused with
//   asrc[i] = ft[i]·att_src, adst[i] = ft[i]·att_dst, per-block col-sums.
// 512 threads, 32 rows x 128 cols per block, thread tile 4 rows x 2 cols.
// grid = 256 blocks (1/CU, 8 waves/CU).
// ---------------------------------------------------------------------------
__global__ void __launch_bounds__(512) gemm_ft_kernel(
    const float* __restrict__ X, const float* __restrict__ W,
    const float* __restrict__ att_src, const float* __restrict__ att_dst,
    float* __restrict__ ft, float* __restrict__ asrc, float* __restrict__ adst,
    float* __restrict__ Spart)
{
  __shared__ float sx[32][36];    // X tile [row][k], pad->aligned b128 + spread banks
  __shared__ float sk[32][132];   // W tile [k][col], pad->aligned b128 writes

  const int tid  = threadIdx.x;
  const int row0 = blockIdx.x * 32;
  const int rg   = tid >> 6;          // wave id 0..7 -> row group
  const int r0   = rg * 4;
  const int c0   = (tid & 63) * 2;    // 2 cols per thread, 64 lanes cover 128
  const int lane = tid & 63;

  float acc[4][2] = {};

  for (int kt = 0; kt < F_IN; kt += 32) {
    if (tid < 256) {
      int row = tid >> 3, kv = (tid & 7) * 4;
      f4v v = *(const f4v*)(X + (size_t)(row0 + row) * F_IN + kt + kv);
      *(f4v*)&sx[row][kv] = v;
    }
    #pragma unroll
    for (int q = 0; q < 2; ++q) {
      int idx = q * 512 + tid;
      int kk  = idx >> 5;
      int cc  = (idx & 31) * 4;
      *(f4v*)&sk[kk][cc] = *(const f4v*)(W + (size_t)(kt + kk) * C_OUT + cc);
    }
    __syncthreads();
    #pragma unroll
    for (int k = 0; k < 32; k += 4) {
      f4v a[4];
      float2 b[4];
      #pragma unroll
      for (int q = 0; q < 4; ++q) a[q] = *(const f4v*)&sx[r0 + q][k];
      #pragma unroll
      for (int q = 0; q < 4; ++q) b[q] = *(const float2*)&sk[k + q][c0];
      #pragma unroll
      for (int i = 0; i < 4; ++i) {
        acc[i][0] += a[i][0] * b[0].x; acc[i][1] += a[i][0] * b[0].y;
        acc[i][0] += a[i][1] * b[1].x; acc[i][1] += a[i][1] * b[1].y;
        acc[i][0] += a[i][2] * b[2].x; acc[i][1] += a[i][2] * b[2].y;
        acc[i][0] += a[i][3] * b[3].x; acc[i][1] += a[i][3] * b[3].y;
      }
    }
    __syncthreads();
  }

  // write ft (coalesced float2 per rg-row)
  #pragma unroll
  for (int i = 0; i < 4; ++i)
    *(float2*)(ft + (size_t)(row0 + r0 + i) * C_OUT + c0) =
        make_float2(acc[i][0], acc[i][1]);

  // asrc/adst: full-wave butterfly over the 64 lanes (covers all 128 cols)
  float2 as = *(const float2*)(att_src + c0);
  float2 ad = *(const float2*)(att_dst + c0);
  #pragma unroll
  for (int i = 0; i < 4; ++i) {
    float ps = acc[i][0] * as.x + acc[i][1] * as.y;
    float pd = acc[i][0] * ad.x + acc[i][1] * ad.y;
    #pragma unroll
    for (int off = 32; off > 0; off >>= 1) {
      ps += __shfl_xor(ps, off);
      pd += __shfl_xor(pd, off);
    }
    if (lane == 0) {
      asrc[row0 + r0 + i] = ps;
      adst[row0 + r0 + i] = pd;
    }
  }

  // column partial sums -> Spart[block][128]  (reuse sx as [8][128])
  float* scp = &sx[0][0];
  float s0 = acc[0][0] + acc[1][0] + acc[2][0] + acc[3][0];
  float s1 = acc[0][1] + acc[1][1] + acc[2][1] + acc[3][1];
  *(float2*)&scp[rg * 128 + c0] = make_float2(s0, s1);
  __syncthreads();
  if (tid < 128) {
    float s = 0.f;
    #pragma unroll
    for (int q = 0; q < 8; ++q) s += scp[q * 128 + tid];
    Spart[(size_t)blockIdx.x * 128 + tid] = s;
  }
}

// ---------------------------------------------------------------------------
// Kernel 2: S[c] = sum over 256 block partials (deterministic, 2 halves)
// ---------------------------------------------------------------------------
__global__ void colsum2_kernel(const float* __restrict__ Spart,
                               float* __restrict__ S)
{
  __shared__ float r2[128];
  const int t = threadIdx.x;
  const int c = t & 127, h = t >> 7;
  float s = 0.f;
  for (int b = h * 128; b < h * 128 + 128; ++b) s += Spart[(size_t)b * 128 + c];
  if (h) r2[c] = s;
  __syncthreads();
  if (!h) S[c] = s + r2[c];
}

// ---------------------------------------------------------------------------
// Kernel 3: one block (256 thr) per row i. Wave-scan edge build (1 barrier),
// no-max softmax (1 reduction), gather. 4 barriers total.
//   out[i] = ( S + sum_e (exp(l_e) - 1) * ft[j_e] ) / denom,
//   denom  = (N - deg) + sum_e exp(l_e)
// ---------------------------------------------------------------------------
__global__ void __launch_bounds__(256) gat_row_kernel(
    const float* __restrict__ adj, const float* __restrict__ ft,
    const float* __restrict__ asrc, const float* __restrict__ adst,
    const float* __restrict__ S, float* __restrict__ out)
{
  __shared__ int   elist[EDGE_CAP];
  __shared__ float evals[EDGE_CAP];
  __shared__ int   wcnt[4];
  __shared__ float wsum[4];
  __shared__ float red[256];

  const int i    = blockIdx.x;
  const int t    = threadIdx.x;
  const int lane = t & 63;
  const int w    = t >> 6;
  const f4v* arow = (const f4v*)(adj + (size_t)i * N_NODES);

  // ---- phase 1: nonzero mask (nontemporal, coalesced)
  unsigned msk = 0u;
  #pragma unroll
  for (int k = 0; k < 8; ++k) {
    f4v v = __builtin_nontemporal_load(&arow[k * 256 + t]);
    unsigned b = 0u;
    if (v[0] != 0.f) b |= 1u;
    if (v[1] != 0.f) b |= 2u;
    if (v[2] != 0.f) b |= 4u;
    if (v[3] != 0.f) b |= 8u;
    msk |= b << (k * 4);
  }
  const int cnt = __popc(msk);

  // wave-level inclusive scan (no barriers)
  int inc = cnt;
  #pragma unroll
  for (int off = 1; off < 64; off <<= 1) {
    int u = __shfl_up(inc, off);
    if (lane >= off) inc += u;
  }
  if (lane == 63) wcnt[w] = inc;
  __syncthreads();

  int base = 0, deg = 0;
  #pragma unroll
  for (int q = 0; q < 4; ++q) {
    int cq = wcnt[q];
    deg += cq;
    if (q < w) base += cq;
  }
  int wo = base + inc - cnt;
  unsigned mm = msk;
  while (mm) {
    int b = __ffs(mm) - 1;
    mm &= mm - 1;
    if (wo < EDGE_CAP)
      elist[wo] = (((b >> 2) * 256 + t) << 2) + (b & 3);
    ++wo;
  }
  __syncthreads();

  const int degc = deg < EDGE_CAP ? deg : EDGE_CAP;
  const float ai = asrc[i];

  // ---- phase 2: exp(leaky(score)), single sum reduction (no max pass)
  float lsum = 0.f;
  for (int e = t; e < degc; e += 256) {
    float s = ai + adst[elist[e]];
    float l = s < 0.f ? NEG_SLOPE * s : s;
    float ev = expf(l);
    evals[e] = ev;
    lsum += ev;
  }
  #pragma unroll
  for (int off = 32; off > 0; off >>= 1) lsum += __shfl_xor(lsum, off);
  if (lane == 0) wsum[w] = lsum;
  __syncthreads();   // evals + wsum visible

  float denom = (float)(N_NODES - deg);
  #pragma unroll
  for (int q = 0; q < 4; ++q) denom += wsum[q];

  // ---- phase 3: gather; 2 edge-parity groups x 128 channels
  const int c = t & 127;
  const int p = t >> 7;
  float a0 = 0.f;
  for (int e = p; e < degc; e += 2)
    a0 += (evals[e] - 1.0f) * ft[(size_t)elist[e] * C_OUT + c];
  red[t] = a0;
  __syncthreads();
  if (t < 128) {
    float o = (S[c] + red[t] + red[t + 128]) / denom;
    out[(size_t)i * C_OUT + c] = o > 0.f ? o : expm1f(o);
  }
}

// ---------------------------------------------------------------------------
extern "C" void kernel_launch(void* const* d_in, const int* in_sizes, int n_in,
                              void* d_out, int out_size, void* d_ws, size_t ws_size,
                              hipStream_t stream)
{
  const float* X       = (const float*)d_in[0];   // features 8192x512
  const float* adj     = (const float*)d_in[1];   // adjacency 8192x8192
  const float* W       = (const float*)d_in[2];   // kernel 512x128
  const float* att_src = (const float*)d_in[3];   // 128
  const float* att_dst = (const float*)d_in[4];   // 128
  float* out = (float*)d_out;

  float* ws    = (float*)d_ws;
  float* ft    = ws;                                   // 8192*128
  float* asrc  = ft + (size_t)N_NODES * C_OUT;         // 8192
  float* adst  = asrc + N_NODES;                       // 8192
  float* Spart = adst + N_NODES;                       // 256*128
  float* S     = Spart + 256 * 128;                    // 128

  gemm_ft_kernel<<<N_NODES / 32, 512, 0, stream>>>(X, W, att_src, att_dst,
                                                   ft, asrc, adst, Spart);
  colsum2_kernel<<<1, 256, 0, stream>>>(Spart, S);
  gat_row_kernel<<<N_NODES, 256, 0, stream>>>(adj, ft, asrc, adst, S, out);
}